// Round 7
// baseline (123.192 us; speedup 1.0000x reference)
//
#include <hip/hip_runtime.h>
#include <hip/hip_bf16.h>

#define SEQ 2048
#define QSTR 4096
// (1/sqrt(128)) * log2(e)
#define CSCALE 0.1275174364688796f

typedef __attribute__((ext_vector_type(8)))  short short8;
typedef __attribute__((ext_vector_type(4)))  float f32x4;
typedef __attribute__((ext_vector_type(16))) float f32x16;

union PF8 { unsigned u[4]; short8 s; };

__device__ __forceinline__ unsigned short f2bf(float f) {
    union { __hip_bfloat16 b; unsigned short u; } cv;
    cv.b = __float2bfloat16(f);
    return cv.u;
}

__device__ __forceinline__ void gload16(const unsigned short* g, unsigned short* l) {
    __builtin_amdgcn_global_load_lds(
        (const __attribute__((address_space(1))) void*)g,
        (__attribute__((address_space(3))) void*)l, 16, 0, 0);
}

// ---- prepass: K -> bf16 [hk][kv][d] ----
__global__ void prep_k(const float* __restrict__ Kg, unsigned short* __restrict__ Kb) {
    int gi = blockIdx.x * 256 + threadIdx.x;
    int kv = gi >> 8;
    int rem = gi & 255;
    int hk = rem >> 5;
    int d4 = rem & 31;
    f32x4 k4 = *(const f32x4*)(Kg + ((size_t)kv * 8 + hk) * 128 + 4 * d4);
    ushort4 u = make_ushort4(f2bf(k4[0]), f2bf(k4[1]), f2bf(k4[2]), f2bf(k4[3]));
    *(ushort4*)(Kb + ((size_t)hk * SEQ + kv) * 128 + 4 * d4) = u;
}

// ---- prepass: V -> bf16 transposed [hk][d][kv] ----
__global__ void prep_v(const float* __restrict__ Vg, unsigned short* __restrict__ Vtb) {
    const int hk  = blockIdx.x >> 5;
    const int kvb = blockIdx.x & 31;
    __shared__ unsigned short T[128][72];
    const int t = threadIdx.x;
    #pragma unroll
    for (int i = 0; i < 8; ++i) {
        int idx = t + 256 * i;
        int r = idx >> 5, d4 = idx & 31;
        f32x4 v = *(const f32x4*)(Vg + ((size_t)(kvb * 64 + r) * 8 + hk) * 128 + 4 * d4);
        T[4 * d4 + 0][r] = f2bf(v[0]);
        T[4 * d4 + 1][r] = f2bf(v[1]);
        T[4 * d4 + 2][r] = f2bf(v[2]);
        T[4 * d4 + 3][r] = f2bf(v[3]);
    }
    __syncthreads();
    #pragma unroll
    for (int i = 0; i < 8; ++i) {
        int idx = t + 256 * i;
        int d = idx >> 4, c4 = idx & 15;
        ushort4 u = *(ushort4*)&T[d][4 * c4];
        *(ushort4*)(Vtb + ((size_t)hk * 128 + d) * SEQ + kvb * 64 + 4 * c4) = u;
    }
}

__launch_bounds__(256, 2)
__global__ void attn_fwd(const float* __restrict__ Qg,
                         const unsigned short* __restrict__ Kb,
                         const unsigned short* __restrict__ Vtb,
                         float* __restrict__ Og) {
    const int bid = blockIdx.x;
    // same-CU pairing: bid and bid+256 share a CU (XCD rr, 256%8==0).
    // Give both the SAME qb -> identical duration -> no solo stretches.
    const int lo  = bid & 255;
    const int qb  = lo >> 4;                     // 0..15
    const int h   = (lo & 15) | ((bid >> 8) << 4);  // 0..31
    const int hk  = h >> 2;
    const int tid  = threadIdx.x;
    const int w    = tid >> 6;
    const int lane = tid & 63;
    const int q5   = lane & 31;
    const int t5   = lane >> 5;
    const int swz  = lane & 7;

    __shared__ __align__(16) unsigned char smem[67584];
    typedef unsigned short KsT[64][128];
    typedef unsigned short VtT[128][64];
    KsT* Ks = (KsT*)smem;                       // Ks[0..1][64][128]
    VtT* Vt = (VtT*)(smem + 32768);             // Vt[0..1][128][64]
    float (*Ot)[132] = (float(*)[132])smem;     // epilogue union

    const int q0w = qb * 128 + 32 * w;          // wave's first q row
    const int nt  = 2 * qb + 2;

    // ---- Q fragments (B operand: col=q5, k=8*t5+e), scale folded ----
    short8 qf[8];
    {
        const float* qp = Qg + (size_t)(q0w + q5) * QSTR + h * 128 + 8 * t5;
        #pragma unroll
        for (int st = 0; st < 8; ++st) {
            f32x4 a = *(const f32x4*)(qp + 16 * st);
            f32x4 b = *(const f32x4*)(qp + 16 * st + 4);
            short8 f;
            f[0] = (short)f2bf(a[0] * CSCALE); f[1] = (short)f2bf(a[1] * CSCALE);
            f[2] = (short)f2bf(a[2] * CSCALE); f[3] = (short)f2bf(a[3] * CSCALE);
            f[4] = (short)f2bf(b[0] * CSCALE); f[5] = (short)f2bf(b[1] * CSCALE);
            f[6] = (short)f2bf(b[2] * CSCALE); f[7] = (short)f2bf(b[3] * CSCALE);
            qf[st] = f;
        }
    }
    // force Q loads/converts to complete so the vmcnt pipeline below is clean
    #pragma unroll
    for (int st = 0; st < 8; ++st) asm volatile("" :: "v"(qf[st]));
    asm volatile("s_waitcnt vmcnt(0)" ::: "memory");

    f32x16 oacc[4];
    #pragma unroll
    for (int dt = 0; dt < 4; ++dt)
        #pragma unroll
        for (int r = 0; r < 16; ++r) oacc[dt][r] = 0.f;
    float m = -1e30f, l = 0.f;

    // staging: wave w -> K rows 16w..16w+15 (4 instr), V rows 32w..32w+31 (4 instr)
    auto ISSUE = [&](int t, int b) {
        const int kv0 = t * 64;
        #pragma unroll
        for (int p = 0; p < 4; ++p) {
            int row = 16 * w + 4 * p + (lane >> 4);
            const unsigned short* g = Kb +
                ((size_t)hk * SEQ + kv0 + row) * 128 + 8 * ((lane & 15) ^ (row & 7));
            gload16(g, &Ks[b][16 * w + 4 * p][0]);
        }
        #pragma unroll
        for (int p = 0; p < 4; ++p) {
            int d = 32 * w + 8 * p + (lane >> 3);
            const unsigned short* g = Vtb +
                ((size_t)hk * 128 + d) * SEQ + kv0 + 8 * ((lane & 7) ^ (d & 7));
            gload16(g, &Vt[b][32 * w + 8 * p][0]);
        }
    };

    ISSUE(0, 0);
    if (nt > 1) ISSUE(1, 1);

    for (int t = 0; t < nt; ++t) {
        const int kv0 = t * 64;
        const int buf = t & 1;
        if (t + 1 < nt) asm volatile("s_waitcnt vmcnt(8)" ::: "memory");
        else            asm volatile("s_waitcnt vmcnt(0)" ::: "memory");
        __builtin_amdgcn_s_barrier();   // tile t staged everywhere; buf^1 free

        const bool active = (kv0 <= q0w + 31);
        if (active) {
            // ---- S^T = K Q^T : D[row=kv][col=q5] ----
            f32x16 sac[2];
            __builtin_amdgcn_s_setprio(1);
            #pragma unroll
            for (int kvs = 0; kvs < 2; ++kvs) {
                f32x16 acc;
                #pragma unroll
                for (int r = 0; r < 16; ++r) acc[r] = 0.f;
                #pragma unroll
                for (int st = 0; st < 8; ++st) {
                    short8 kf = *(const short8*)
                        &Ks[buf][32 * kvs + q5][8 * ((2 * st + t5) ^ swz)];
                    acc = __builtin_amdgcn_mfma_f32_32x32x16_bf16(kf, qf[st], acc, 0, 0, 0);
                }
                sac[kvs] = acc;
            }
            __builtin_amdgcn_s_setprio(0);

            // ---- mask (diagonal tiles only) ----
            if (kv0 + 63 > q0w) {
                const int qrow = q0w + q5;
                #pragma unroll
                for (int kvs = 0; kvs < 2; ++kvs)
                    #pragma unroll
                    for (int r = 0; r < 16; ++r) {
                        int kv = kv0 + 32 * kvs + (r & 3) + 8 * (r >> 2) + 4 * t5;
                        if (kv > qrow) sac[kvs][r] = -1e30f;
                    }
            }

            // ---- row max: depth-5 tree + one cross-lane ----
            float t16[16], t8[8], t4[4], t2[2];
            #pragma unroll
            for (int i = 0; i < 16; ++i) t16[i] = fmaxf(sac[0][i], sac[1][i]);
            #pragma unroll
            for (int i = 0; i < 8; ++i) t8[i] = fmaxf(t16[i], t16[i + 8]);
            #pragma unroll
            for (int i = 0; i < 4; ++i) t4[i] = fmaxf(t8[i], t8[i + 4]);
            t2[0] = fmaxf(t4[0], t4[2]); t2[1] = fmaxf(t4[1], t4[3]);
            float mx = fmaxf(t2[0], t2[1]);
            mx = fmaxf(mx, __shfl_xor(mx, 32));

            // ---- defer-max (T13): skip O-rescale when growth small ----
            const bool skip = __all(mx <= m + 11.0f);
            float fac = 1.0f;
            if (!skip) {
                float mn = fmaxf(m, mx);
                fac = exp2f(m - mn);
                m = mn;
            }

            // ---- P = 2^(S-m); depth-5 tree sum ----
            float ps;
            {
                #pragma unroll
                for (int kvs = 0; kvs < 2; ++kvs)
                    #pragma unroll
                    for (int r = 0; r < 16; ++r)
                        sac[kvs][r] = exp2f(sac[kvs][r] - m);
                float s16[16], s8[8], s4[4], s2[2];
                #pragma unroll
                for (int i = 0; i < 16; ++i) s16[i] = sac[0][i] + sac[1][i];
                #pragma unroll
                for (int i = 0; i < 8; ++i) s8[i] = s16[i] + s16[i + 8];
                #pragma unroll
                for (int i = 0; i < 4; ++i) s4[i] = s8[i] + s8[i + 4];
                s2[0] = s4[0] + s4[2]; s2[1] = s4[1] + s4[3];
                ps = s2[0] + s2[1];
                ps += __shfl_xor(ps, 32);
            }
            if (!skip) {
                l = l * fac + ps;
                #pragma unroll
                for (int dt = 0; dt < 4; ++dt)
                    #pragma unroll
                    for (int r = 0; r < 16; ++r) oacc[dt][r] *= fac;
            } else {
                l += ps;
            }

            // ---- pack P pairs to bf16x2 ----
            unsigned pkw[2][8];
            #pragma unroll
            for (int a = 0; a < 2; ++a)
                #pragma unroll
                for (int rp = 0; rp < 8; ++rp)
                    pkw[a][rp] = (unsigned)f2bf(sac[a][2 * rp]) |
                                 ((unsigned)f2bf(sac[a][2 * rp + 1]) << 16);

            // ---- redistribute to PV B-fragments (cross-half only) ----
            unsigned xp[2][8];
            #pragma unroll
            for (int a = 0; a < 2; ++a)
                #pragma unroll
                for (int i = 0; i < 8; ++i)
                    xp[a][i] = (unsigned)__shfl_xor((int)pkw[a][i], 32);

            PF8 pf[4];
            #pragma unroll
            for (int ks = 0; ks < 4; ++ks) {
                const int a = ks >> 1;
                #pragma unroll
                for (int j = 0; j < 4; ++j) {
                    const int ib = (j & 1) + 4 * (ks & 1);
                    const unsigned own_lo = pkw[a][ib];
                    const unsigned own_hi = pkw[a][ib + 2];
                    const unsigned par_lo = xp[a][ib];
                    const unsigned par_hi = xp[a][ib + 2];
                    pf[ks].u[j] = (j < 2) ? (t5 ? par_hi : own_lo)
                                          : (t5 ? own_hi : par_lo);
                }
            }

            // ---- O^T += V^T P ----
            __builtin_amdgcn_s_setprio(1);
            #pragma unroll
            for (int dt = 0; dt < 4; ++dt) {
                #pragma unroll
                for (int ks = 0; ks < 4; ++ks) {
                    short8 vf = *(const short8*)
                        &Vt[buf][32 * dt + q5][8 * ((2 * ks + t5) ^ swz)];
                    oacc[dt] = __builtin_amdgcn_mfma_f32_32x32x16_bf16(vf, pf[ks].s, oacc[dt], 0, 0, 0);
                }
            }
            __builtin_amdgcn_s_setprio(0);
        }

        asm volatile("" ::: "memory");
        __builtin_amdgcn_s_barrier();           // all waves done reading buf
        if (t + 2 < nt) ISSUE(t + 2, buf);      // flies across compute(t+1)
    }

    // ---- epilogue: transpose O^T through LDS, coalesced fp32 stores ----
    asm volatile("" ::: "memory");
    const float rl = 1.0f / l;
    #pragma unroll
    for (int dt = 0; dt < 4; ++dt)
        #pragma unroll
        for (int b = 0; b < 4; ++b) {
            f32x4 v;
            v[0] = oacc[dt][4 * b + 0] * rl;
            v[1] = oacc[dt][4 * b + 1] * rl;
            v[2] = oacc[dt][4 * b + 2] * rl;
            v[3] = oacc[dt][4 * b + 3] * rl;
            *(f32x4*)&Ot[32 * w + q5][32 * dt + 8 * b + 4 * t5] = v;
        }
    __syncthreads();
    {
        const int col4 = (tid & 31) * 4;
        const int r0   = tid >> 5;
        float* ob = Og + (size_t)(qb * 128) * QSTR + h * 128;
        #pragma unroll
        for (int i = 0; i < 16; ++i) {
            int row = 8 * i + r0;
            f32x4 v = *(const f32x4*)&Ot[row][col4];
            *(f32x4*)(ob + (size_t)row * QSTR + col4) = v;
        }
    }
}

extern "C" void kernel_launch(void* const* d_in, const int* in_sizes, int n_in,
                              void* d_out, int out_size, void* d_ws, size_t ws_size,
                              hipStream_t stream) {
    const float* q = (const float*)d_in[0];
    const float* k = (const float*)d_in[1];
    const float* v = (const float*)d_in[2];
    float* out = (float*)d_out;
    unsigned short* Kb  = (unsigned short*)d_ws;                 // 4 MB
    unsigned short* Vtb = Kb + (size_t)8 * SEQ * 128;            // 4 MB
    prep_k<<<dim3(2048), 256, 0, stream>>>(k, Kb);
    prep_v<<<dim3(256), 256, 0, stream>>>(v, Vtb);
    attn_fwd<<<dim3(512), 256, 0, stream>>>(q, Kb, Vtb, out);
}

// Round 8
// 98.311 us; speedup vs baseline: 1.2531x; 1.2531x over previous
//
#include <hip/hip_runtime.h>
#include <hip/hip_bf16.h>

#define SEQ 2048
#define QSTR 4096
// (1/sqrt(128)) * log2(e)
#define CSCALE 0.1275174364688796f

typedef __attribute__((ext_vector_type(8)))  short short8;
typedef __attribute__((ext_vector_type(4)))  float f32x4;
typedef __attribute__((ext_vector_type(16))) float f32x16;

union PF8 { unsigned u[4]; short8 s; };

__device__ __forceinline__ unsigned short f2bf(float f) {
    union { __hip_bfloat16 b; unsigned short u; } cv;
    cv.b = __float2bfloat16(f);
    return cv.u;
}

__device__ __forceinline__ void gload16(const unsigned short* g, unsigned short* l) {
    __builtin_amdgcn_global_load_lds(
        (const __attribute__((address_space(1))) void*)g,
        (__attribute__((address_space(3))) void*)l, 16, 0, 0);
}

// ---- prepass: K -> bf16 [hk][kv][d] ----
__global__ void prep_k(const float* __restrict__ Kg, unsigned short* __restrict__ Kb) {
    int gi = blockIdx.x * 256 + threadIdx.x;
    int kv = gi >> 8;
    int rem = gi & 255;
    int hk = rem >> 5;
    int d4 = rem & 31;
    f32x4 k4 = *(const f32x4*)(Kg + ((size_t)kv * 8 + hk) * 128 + 4 * d4);
    ushort4 u = make_ushort4(f2bf(k4[0]), f2bf(k4[1]), f2bf(k4[2]), f2bf(k4[3]));
    *(ushort4*)(Kb + ((size_t)hk * SEQ + kv) * 128 + 4 * d4) = u;
}

// ---- prepass: V -> bf16 transposed [hk][d][kv] ----
__global__ void prep_v(const float* __restrict__ Vg, unsigned short* __restrict__ Vtb) {
    const int hk  = blockIdx.x >> 5;
    const int kvb = blockIdx.x & 31;
    __shared__ unsigned short T[128][72];
    const int t = threadIdx.x;
    #pragma unroll
    for (int i = 0; i < 8; ++i) {
        int idx = t + 256 * i;
        int r = idx >> 5, d4 = idx & 31;
        f32x4 v = *(const f32x4*)(Vg + ((size_t)(kvb * 64 + r) * 8 + hk) * 128 + 4 * d4);
        T[4 * d4 + 0][r] = f2bf(v[0]);
        T[4 * d4 + 1][r] = f2bf(v[1]);
        T[4 * d4 + 2][r] = f2bf(v[2]);
        T[4 * d4 + 3][r] = f2bf(v[3]);
    }
    __syncthreads();
    #pragma unroll
    for (int i = 0; i < 8; ++i) {
        int idx = t + 256 * i;
        int d = idx >> 4, c4 = idx & 15;
        ushort4 u = *(ushort4*)&T[d][4 * c4];
        *(ushort4*)(Vtb + ((size_t)hk * 128 + d) * SEQ + kvb * 64 + 4 * c4) = u;
    }
}

__launch_bounds__(256, 2)
__global__ void attn_fwd(const float* __restrict__ Qg,
                         const unsigned short* __restrict__ Kb,
                         const unsigned short* __restrict__ Vtb,
                         float* __restrict__ Og) {
    const int bid = blockIdx.x;
    const int qb  = bid >> 5;          // 0..15: this block owns q-blocks (qb, 31-qb)
    const int h   = bid & 31;
    const int hk  = h >> 2;
    const int tid  = threadIdx.x;
    const int w    = tid >> 6;         // waves 0-1 -> sub-block A (qb), 2-3 -> B (31-qb)
    const int lane = tid & 63;
    const int q5   = lane & 31;
    const int t5   = lane >> 5;
    const int swz  = lane & 7;

    __shared__ __align__(16) unsigned char smem[67584];
    typedef unsigned short KsT[64][128];
    typedef unsigned short VtT[128][64];
    KsT* Ks = (KsT*)smem;                       // Ks[0..1][64][128]
    VtT* Vt = (VtT*)(smem + 32768);             // Vt[0..1][128][64]
    float (*Ot)[132] = (float(*)[132])smem;     // epilogue union

    const int qblk = (w >> 1) ? (31 - qb) : qb;
    const int q0w  = qblk * 64 + 32 * (w & 1);  // wave's first q row
    const int nt   = 32 - qb;                   // kv tiles 0..31-qb (B's range)

    // ---- Q fragments (B operand: col=q5, k=8*t5+e), scale folded ----
    short8 qf[8];
    {
        const float* qp = Qg + (size_t)(q0w + q5) * QSTR + h * 128 + 8 * t5;
        #pragma unroll
        for (int st = 0; st < 8; ++st) {
            f32x4 a = *(const f32x4*)(qp + 16 * st);
            f32x4 b = *(const f32x4*)(qp + 16 * st + 4);
            short8 f;
            f[0] = (short)f2bf(a[0] * CSCALE); f[1] = (short)f2bf(a[1] * CSCALE);
            f[2] = (short)f2bf(a[2] * CSCALE); f[3] = (short)f2bf(a[3] * CSCALE);
            f[4] = (short)f2bf(b[0] * CSCALE); f[5] = (short)f2bf(b[1] * CSCALE);
            f[6] = (short)f2bf(b[2] * CSCALE); f[7] = (short)f2bf(b[3] * CSCALE);
            qf[st] = f;
        }
    }
    // force Q loads/converts to complete so the vmcnt pipeline below is clean
    #pragma unroll
    for (int st = 0; st < 8; ++st) asm volatile("" :: "v"(qf[st]));
    asm volatile("s_waitcnt vmcnt(0)" ::: "memory");

    f32x16 oacc[4];
    #pragma unroll
    for (int dt = 0; dt < 4; ++dt)
        #pragma unroll
        for (int r = 0; r < 16; ++r) oacc[dt][r] = 0.f;
    float m = -1e30f, l = 0.f;

    // staging: wave w -> K rows 16w..16w+15 (4 instr), V rows 32w..32w+31 (4 instr)
    auto ISSUE = [&](int t, int b) {
        const int kv0 = t * 64;
        #pragma unroll
        for (int p = 0; p < 4; ++p) {
            int row = 16 * w + 4 * p + (lane >> 4);
            const unsigned short* g = Kb +
                ((size_t)hk * SEQ + kv0 + row) * 128 + 8 * ((lane & 15) ^ (row & 7));
            gload16(g, &Ks[b][16 * w + 4 * p][0]);
        }
        #pragma unroll
        for (int p = 0; p < 4; ++p) {
            int d = 32 * w + 8 * p + (lane >> 3);
            const unsigned short* g = Vtb +
                ((size_t)hk * 128 + d) * SEQ + kv0 + 8 * ((lane & 7) ^ (d & 7));
            gload16(g, &Vt[b][32 * w + 8 * p][0]);
        }
    };

    ISSUE(0, 0);
    ISSUE(1, 1);                                 // nt >= 17 always

    for (int t = 0; t < nt; ++t) {
        const int kv0 = t * 64;
        const int buf = t & 1;
        if (t + 1 < nt) asm volatile("s_waitcnt vmcnt(8)" ::: "memory");
        else            asm volatile("s_waitcnt vmcnt(0)" ::: "memory");
        __builtin_amdgcn_s_barrier();   // tile t staged everywhere; buf^1 free

        const bool active = (kv0 <= q0w + 31);
        if (active) {
            // ---- S^T = K Q^T : D[row=kv][col=q5] ----
            f32x16 sac[2];
            __builtin_amdgcn_s_setprio(1);
            #pragma unroll
            for (int kvs = 0; kvs < 2; ++kvs) {
                f32x16 acc;
                #pragma unroll
                for (int r = 0; r < 16; ++r) acc[r] = 0.f;
                #pragma unroll
                for (int st = 0; st < 8; ++st) {
                    short8 kf = *(const short8*)
                        &Ks[buf][32 * kvs + q5][8 * ((2 * st + t5) ^ swz)];
                    acc = __builtin_amdgcn_mfma_f32_32x32x16_bf16(kf, qf[st], acc, 0, 0, 0);
                }
                sac[kvs] = acc;
            }
            __builtin_amdgcn_s_setprio(0);

            // ---- mask (diagonal tiles only) ----
            if (kv0 + 63 > q0w) {
                const int qrow = q0w + q5;
                #pragma unroll
                for (int kvs = 0; kvs < 2; ++kvs)
                    #pragma unroll
                    for (int r = 0; r < 16; ++r) {
                        int kv = kv0 + 32 * kvs + (r & 3) + 8 * (r >> 2) + 4 * t5;
                        if (kv > qrow) sac[kvs][r] = -1e30f;
                    }
            }

            // ---- row max: depth-5 tree + one cross-lane ----
            float t16[16], t8[8], t4[4], t2[2];
            #pragma unroll
            for (int i = 0; i < 16; ++i) t16[i] = fmaxf(sac[0][i], sac[1][i]);
            #pragma unroll
            for (int i = 0; i < 8; ++i) t8[i] = fmaxf(t16[i], t16[i + 8]);
            #pragma unroll
            for (int i = 0; i < 4; ++i) t4[i] = fmaxf(t8[i], t8[i + 4]);
            t2[0] = fmaxf(t4[0], t4[2]); t2[1] = fmaxf(t4[1], t4[3]);
            float mx = fmaxf(t2[0], t2[1]);
            mx = fmaxf(mx, __shfl_xor(mx, 32));

            // ---- defer-max (T13): skip O-rescale when growth small ----
            const bool skip = __all(mx <= m + 11.0f);
            float fac = 1.0f;
            if (!skip) {
                float mn = fmaxf(m, mx);
                fac = exp2f(m - mn);
                m = mn;
            }

            // ---- P = 2^(S-m); depth-5 tree sum ----
            float ps;
            {
                #pragma unroll
                for (int kvs = 0; kvs < 2; ++kvs)
                    #pragma unroll
                    for (int r = 0; r < 16; ++r)
                        sac[kvs][r] = exp2f(sac[kvs][r] - m);
                float s16[16], s8[8], s4[4], s2[2];
                #pragma unroll
                for (int i = 0; i < 16; ++i) s16[i] = sac[0][i] + sac[1][i];
                #pragma unroll
                for (int i = 0; i < 8; ++i) s8[i] = s16[i] + s16[i + 8];
                #pragma unroll
                for (int i = 0; i < 4; ++i) s4[i] = s8[i] + s8[i + 4];
                s2[0] = s4[0] + s4[2]; s2[1] = s4[1] + s4[3];
                ps = s2[0] + s2[1];
                ps += __shfl_xor(ps, 32);
            }
            if (!skip) {
                l = l * fac + ps;
                #pragma unroll
                for (int dt = 0; dt < 4; ++dt)
                    #pragma unroll
                    for (int r = 0; r < 16; ++r) oacc[dt][r] *= fac;
            } else {
                l += ps;
            }

            // ---- pack P pairs to bf16x2 ----
            unsigned pkw[2][8];
            #pragma unroll
            for (int a = 0; a < 2; ++a)
                #pragma unroll
                for (int rp = 0; rp < 8; ++rp)
                    pkw[a][rp] = (unsigned)f2bf(sac[a][2 * rp]) |
                                 ((unsigned)f2bf(sac[a][2 * rp + 1]) << 16);

            // ---- redistribute to PV B-fragments (cross-half only) ----
            unsigned xp[2][8];
            #pragma unroll
            for (int a = 0; a < 2; ++a)
                #pragma unroll
                for (int i = 0; i < 8; ++i)
                    xp[a][i] = (unsigned)__shfl_xor((int)pkw[a][i], 32);

            PF8 pf[4];
            #pragma unroll
            for (int ks = 0; ks < 4; ++ks) {
                const int a = ks >> 1;
                #pragma unroll
                for (int j = 0; j < 4; ++j) {
                    const int ib = (j & 1) + 4 * (ks & 1);
                    const unsigned own_lo = pkw[a][ib];
                    const unsigned own_hi = pkw[a][ib + 2];
                    const unsigned par_lo = xp[a][ib];
                    const unsigned par_hi = xp[a][ib + 2];
                    pf[ks].u[j] = (j < 2) ? (t5 ? par_hi : own_lo)
                                          : (t5 ? own_hi : par_lo);
                }
            }

            // ---- O^T += V^T P ----
            __builtin_amdgcn_s_setprio(1);
            #pragma unroll
            for (int dt = 0; dt < 4; ++dt) {
                #pragma unroll
                for (int ks = 0; ks < 4; ++ks) {
                    short8 vf = *(const short8*)
                        &Vt[buf][32 * dt + q5][8 * ((2 * ks + t5) ^ swz)];
                    oacc[dt] = __builtin_amdgcn_mfma_f32_32x32x16_bf16(vf, pf[ks].s, oacc[dt], 0, 0, 0);
                }
            }
            __builtin_amdgcn_s_setprio(0);
        }

        asm volatile("" ::: "memory");
        __builtin_amdgcn_s_barrier();           // all waves done reading buf
        if (t + 2 < nt) ISSUE(t + 2, buf);      // flies across compute(t+1)
    }

    // ---- epilogue: transpose O^T through LDS, coalesced fp32 stores ----
    // Ot rows 0..63 = sub-block A (q-block qb), rows 64..127 = B (31-qb)
    asm volatile("" ::: "memory");
    const float rl = 1.0f / l;
    #pragma unroll
    for (int dt = 0; dt < 4; ++dt)
        #pragma unroll
        for (int b = 0; b < 4; ++b) {
            f32x4 v;
            v[0] = oacc[dt][4 * b + 0] * rl;
            v[1] = oacc[dt][4 * b + 1] * rl;
            v[2] = oacc[dt][4 * b + 2] * rl;
            v[3] = oacc[dt][4 * b + 3] * rl;
            *(f32x4*)&Ot[32 * w + q5][32 * dt + 8 * b + 4 * t5] = v;
        }
    __syncthreads();
    {
        const int col4 = (tid & 31) * 4;
        const int r0   = tid >> 5;
        float* ob = Og + h * 128;
        #pragma unroll
        for (int i = 0; i < 16; ++i) {
            int row = 8 * i + r0;
            int grow = (row < 64) ? (qb * 64 + row) : ((31 - qb) * 64 + row - 64);
            f32x4 v = *(const f32x4*)&Ot[row][col4];
            *(f32x4*)(ob + (size_t)grow * QSTR + col4) = v;
        }
    }
}

extern "C" void kernel_launch(void* const* d_in, const int* in_sizes, int n_in,
                              void* d_out, int out_size, void* d_ws, size_t ws_size,
                              hipStream_t stream) {
    const float* q = (const float*)d_in[0];
    const float* k = (const float*)d_in[1];
    const float* v = (const float*)d_in[2];
    float* out = (float*)d_out;
    unsigned short* Kb  = (unsigned short*)d_ws;                 // 4 MB
    unsigned short* Vtb = Kb + (size_t)8 * SEQ * 128;            // 4 MB
    prep_k<<<dim3(2048), 256, 0, stream>>>(k, Kb);
    prep_v<<<dim3(256), 256, 0, stream>>>(v, Vtb);
    attn_fwd<<<dim3(512), 256, 0, stream>>>(q, Kb, Vtb, out);
}

// Round 9
// 89.287 us; speedup vs baseline: 1.3797x; 1.1011x over previous
//
#include <hip/hip_runtime.h>
#include <hip/hip_bf16.h>

#define SEQ 2048
#define QSTR 4096
// (1/sqrt(128)) * log2(e)
#define CSCALE 0.1275174364688796f

typedef __attribute__((ext_vector_type(8)))  short short8;
typedef __attribute__((ext_vector_type(4)))  float f32x4;
typedef __attribute__((ext_vector_type(16))) float f32x16;

union PF8 { unsigned u[4]; short8 s; };

__device__ __forceinline__ unsigned short f2bf(float f) {
    union { __hip_bfloat16 b; unsigned short u; } cv;
    cv.b = __float2bfloat16(f);
    return cv.u;
}

__device__ __forceinline__ void gload16(const unsigned short* g, unsigned short* l) {
    __builtin_amdgcn_global_load_lds(
        (const __attribute__((address_space(1))) void*)g,
        (__attribute__((address_space(3))) void*)l, 16, 0, 0);
}

// ---- prepass: K -> bf16 [hk][kv][d] ----
__global__ void prep_k(const float* __restrict__ Kg, unsigned short* __restrict__ Kb) {
    int gi = blockIdx.x * 256 + threadIdx.x;
    int kv = gi >> 8;
    int rem = gi & 255;
    int hk = rem >> 5;
    int d4 = rem & 31;
    f32x4 k4 = *(const f32x4*)(Kg + ((size_t)kv * 8 + hk) * 128 + 4 * d4);
    ushort4 u = make_ushort4(f2bf(k4[0]), f2bf(k4[1]), f2bf(k4[2]), f2bf(k4[3]));
    *(ushort4*)(Kb + ((size_t)hk * SEQ + kv) * 128 + 4 * d4) = u;
}

// ---- prepass: V -> bf16 transposed [hk][d][kv] ----
__global__ void prep_v(const float* __restrict__ Vg, unsigned short* __restrict__ Vtb) {
    const int hk  = blockIdx.x >> 5;
    const int kvb = blockIdx.x & 31;
    __shared__ unsigned short T[128][72];
    const int t = threadIdx.x;
    #pragma unroll
    for (int i = 0; i < 8; ++i) {
        int idx = t + 256 * i;
        int r = idx >> 5, d4 = idx & 31;
        f32x4 v = *(const f32x4*)(Vg + ((size_t)(kvb * 64 + r) * 8 + hk) * 128 + 4 * d4);
        T[4 * d4 + 0][r] = f2bf(v[0]);
        T[4 * d4 + 1][r] = f2bf(v[1]);
        T[4 * d4 + 2][r] = f2bf(v[2]);
        T[4 * d4 + 3][r] = f2bf(v[3]);
    }
    __syncthreads();
    #pragma unroll
    for (int i = 0; i < 8; ++i) {
        int idx = t + 256 * i;
        int d = idx >> 4, c4 = idx & 15;
        ushort4 u = *(ushort4*)&T[d][4 * c4];
        *(ushort4*)(Vtb + ((size_t)hk * 128 + d) * SEQ + kvb * 64 + 4 * c4) = u;
    }
}

__launch_bounds__(512, 2)
__global__ void attn_fwd(const float* __restrict__ Qg,
                         const unsigned short* __restrict__ Kb,
                         const unsigned short* __restrict__ Vtb,
                         float* __restrict__ Og) {
    const int bid = blockIdx.x;            // 256 blocks, 1 per CU (LDS-capped)
    const int pr  = bid >> 5;              // 0..7 pair index
    const int h   = bid & 31;
    const int hk  = h >> 2;
    const int QBb = 15 - pr;               // big superblock (rows 128*QBb..+127)
    const int QBa = pr;                    // small superblock
    const int nsB = QBb + 1;               // 9..16
    // nsA = QBa + 1; nsB + nsA == 17 for every block

    const int tid  = threadIdx.x;
    const int w    = tid >> 6;             // 0..7
    const int wq   = w & 3;                // q band
    const int wk   = w >> 2;               // kv half
    const int lane = tid & 63;
    const int q5   = lane & 31;
    const int t5   = lane >> 5;
    const int swz  = lane & 7;

    __shared__ __align__(16) unsigned char smem[150016];
    typedef unsigned short TileT[128][128];
    TileT* Ks = (TileT*)smem;                           // 2 x 32 KB
    TileT* Vt = (TileT*)(smem + 65536);                 // 2 x 32 KB
    float* mlm = (float*)(smem + 131072);               // [8][32]
    float* mll = (float*)(smem + 132096);               // [8][32]
    float (*Ot)[132] = (float(*)[132])(smem + 133120);  // [32][132] transpose scratch

    // ---- Q fragments (working set; reloaded at phase switch) ----
    short8 qf[8];
    auto LOADQ = [&](int QB) __attribute__((always_inline)) {
        const float* qp = Qg + (size_t)(QB * 128 + 32 * wq + q5) * QSTR + h * 128 + 8 * t5;
        #pragma unroll
        for (int st = 0; st < 8; ++st) {
            f32x4 a = *(const f32x4*)(qp + 16 * st);
            f32x4 b = *(const f32x4*)(qp + 16 * st + 4);
            short8 f;
            f[0] = (short)f2bf(a[0] * CSCALE); f[1] = (short)f2bf(a[1] * CSCALE);
            f[2] = (short)f2bf(a[2] * CSCALE); f[3] = (short)f2bf(a[3] * CSCALE);
            f[4] = (short)f2bf(b[0] * CSCALE); f[5] = (short)f2bf(b[1] * CSCALE);
            f[6] = (short)f2bf(b[2] * CSCALE); f[7] = (short)f2bf(b[3] * CSCALE);
            qf[st] = f;
        }
    };

    auto ISSUE = [&](int kv0, int b) __attribute__((always_inline)) {
        #pragma unroll
        for (int p4 = 0; p4 < 4; ++p4) {
            int row = 16 * w + 4 * p4 + (lane >> 4);
            const unsigned short* g = Kb +
                ((size_t)hk * SEQ + kv0 + row) * 128 + 8 * ((lane & 15) ^ (row & 7));
            gload16(g, &Ks[b][16 * w + 4 * p4][0]);
        }
        #pragma unroll
        for (int p4 = 0; p4 < 4; ++p4) {
            int d = 16 * w + 4 * p4 + (lane >> 4);
            const unsigned short* g = Vtb +
                ((size_t)hk * 128 + d) * SEQ + kv0 + 8 * ((lane & 15) ^ (d & 7));
            gload16(g, &Vt[b][16 * w + 4 * p4][0]);
        }
    };

    f32x16 oacc[4];
    float m, l;
    auto RESET = [&]() __attribute__((always_inline)) {
        #pragma unroll
        for (int dt = 0; dt < 4; ++dt)
            #pragma unroll
            for (int r = 0; r < 16; ++r) oacc[dt][r] = 0.f;
        m = -1e30f; l = 0.f;
    };

    // phase-end: combine kv-half partials (flash-decoding algebra) + store
    auto EPI = [&](int QBp) __attribute__((always_inline)) {
        if (t5 == 0) mlm[w * 32 + q5] = m;
        asm volatile("s_waitcnt lgkmcnt(0)" ::: "memory");
        __builtin_amdgcn_sched_barrier(0);
        __builtin_amdgcn_s_barrier();
        const float mOth = mlm[(w ^ 4) * 32 + q5];
        const float M  = fmaxf(m, mOth);
        const float sc = exp2f(m - M);
        const float lp = l * sc;
        #pragma unroll
        for (int dt = 0; dt < 4; ++dt)
            #pragma unroll
            for (int r = 0; r < 16; ++r) oacc[dt][r] *= sc;
        if (t5 == 0) mll[w * 32 + q5] = lp;
        asm volatile("s_waitcnt lgkmcnt(0)" ::: "memory");
        __builtin_amdgcn_sched_barrier(0);
        __builtin_amdgcn_s_barrier();
        const float lOth = mll[(w ^ 4) * 32 + q5];

        #pragma unroll 1
        for (int tq = 0; tq < 4; ++tq) {
            if (w == tq + 4) {            // kv-half-1 wave of band tq: publish partial
                #pragma unroll
                for (int dt = 0; dt < 4; ++dt)
                    #pragma unroll
                    for (int b = 0; b < 4; ++b) {
                        f32x4 v;
                        v[0] = oacc[dt][4 * b + 0]; v[1] = oacc[dt][4 * b + 1];
                        v[2] = oacc[dt][4 * b + 2]; v[3] = oacc[dt][4 * b + 3];
                        *(f32x4*)&Ot[q5][32 * dt + 8 * b + 4 * t5] = v;
                    }
            }
            asm volatile("s_waitcnt lgkmcnt(0)" ::: "memory");
            __builtin_amdgcn_sched_barrier(0);
            __builtin_amdgcn_s_barrier();
            if (w == tq) {                // kv-half-0 wave: combine + normalize
                const float rl = 1.0f / (lp + lOth);
                #pragma unroll
                for (int dt = 0; dt < 4; ++dt)
                    #pragma unroll
                    for (int b = 0; b < 4; ++b) {
                        f32x4 o1 = *(const f32x4*)&Ot[q5][32 * dt + 8 * b + 4 * t5];
                        f32x4 oc;
                        oc[0] = (oacc[dt][4 * b + 0] + o1[0]) * rl;
                        oc[1] = (oacc[dt][4 * b + 1] + o1[1]) * rl;
                        oc[2] = (oacc[dt][4 * b + 2] + o1[2]) * rl;
                        oc[3] = (oacc[dt][4 * b + 3] + o1[3]) * rl;
                        *(f32x4*)&Ot[q5][32 * dt + 8 * b + 4 * t5] = oc;
                    }
            }
            asm volatile("s_waitcnt lgkmcnt(0)" ::: "memory");
            __builtin_amdgcn_sched_barrier(0);
            __builtin_amdgcn_s_barrier();
            {   // all 512 threads: coalesced store of rows 128*QBp + 32*tq ..+31
                float* ob = Og + (size_t)(QBp * 128 + 32 * tq) * QSTR + h * 128;
                #pragma unroll
                for (int i = 0; i < 2; ++i) {
                    int u  = tid + 512 * i;        // 0..1023
                    int r  = u >> 5;
                    int c4 = (u & 31) * 4;
                    f32x4 v = *(const f32x4*)&Ot[r][c4];
                    *(f32x4*)(ob + (size_t)r * QSTR + c4) = v;
                }
            }
            asm volatile("s_waitcnt lgkmcnt(0)" ::: "memory");
            __builtin_amdgcn_sched_barrier(0);
            __builtin_amdgcn_s_barrier();
        }
    };

    LOADQ(QBb);
    #pragma unroll
    for (int st = 0; st < 8; ++st) asm volatile("" :: "v"(qf[st]));
    asm volatile("s_waitcnt vmcnt(0)" ::: "memory");
    RESET();

    ISSUE(0, 0);
    ISSUE(128, 1);    // nsB >= 9, so step 1 is always a B tile

    for (int s = 0; s < 17; ++s) {
        if (s == nsB) {               // phase switch: B done -> A
            LOADQ(QBa);               // flies during EPI
            EPI(QBb);
            RESET();
        }
        const bool isB = (s < nsB);
        const int kv0   = isB ? 128 * s : 128 * (s - nsB);
        const int q0blk = isB ? 128 * QBb : 128 * QBa;
        const int buf = s & 1;

        if (s + 1 < 17) asm volatile("s_waitcnt vmcnt(8)" ::: "memory");
        else            asm volatile("s_waitcnt vmcnt(0)" ::: "memory");
        __builtin_amdgcn_s_barrier();

        const int q0w = q0blk + 32 * wq;
        const int kvb = kv0 + 64 * wk;         // this wave's kv-half base
        if (kvb <= q0w + 31) {
            // ---- S^T = K Q^T on own kv-half ----
            f32x16 sac[2];
            __builtin_amdgcn_s_setprio(1);
            #pragma unroll
            for (int kvs = 0; kvs < 2; ++kvs) {
                f32x16 acc;
                #pragma unroll
                for (int r = 0; r < 16; ++r) acc[r] = 0.f;
                #pragma unroll
                for (int st = 0; st < 8; ++st) {
                    short8 kf = *(const short8*)
                        &Ks[buf][64 * wk + 32 * kvs + q5][8 * ((2 * st + t5) ^ swz)];
                    acc = __builtin_amdgcn_mfma_f32_32x32x16_bf16(kf, qf[st], acc, 0, 0, 0);
                }
                sac[kvs] = acc;
            }
            __builtin_amdgcn_s_setprio(0);

            // ---- mask (diagonal only) ----
            if (kvb + 63 > q0w) {
                const int qrow = q0w + q5;
                #pragma unroll
                for (int kvs = 0; kvs < 2; ++kvs)
                    #pragma unroll
                    for (int r = 0; r < 16; ++r) {
                        int kv = kvb + 32 * kvs + (r & 3) + 8 * (r >> 2) + 4 * t5;
                        if (kv > qrow) sac[kvs][r] = -1e30f;
                    }
            }

            // ---- row max: depth-5 tree + one cross-lane ----
            float t16[16], t8[8], t4[4], t2[2];
            #pragma unroll
            for (int i = 0; i < 16; ++i) t16[i] = fmaxf(sac[0][i], sac[1][i]);
            #pragma unroll
            for (int i = 0; i < 8; ++i) t8[i] = fmaxf(t16[i], t16[i + 8]);
            #pragma unroll
            for (int i = 0; i < 4; ++i) t4[i] = fmaxf(t8[i], t8[i + 4]);
            t2[0] = fmaxf(t4[0], t4[2]); t2[1] = fmaxf(t4[1], t4[3]);
            float mx = fmaxf(t2[0], t2[1]);
            mx = fmaxf(mx, __shfl_xor(mx, 32));

            // ---- defer-max (T13) ----
            const bool skip = __all(mx <= m + 11.0f);
            float fac = 1.0f;
            if (!skip) {
                float mn = fmaxf(m, mx);
                fac = exp2f(m - mn);
                m = mn;
            }

            // ---- P = 2^(S-m); depth-5 tree sum ----
            float ps;
            {
                #pragma unroll
                for (int kvs = 0; kvs < 2; ++kvs)
                    #pragma unroll
                    for (int r = 0; r < 16; ++r)
                        sac[kvs][r] = exp2f(sac[kvs][r] - m);
                float s16[16], s8[8], s4[4], s2[2];
                #pragma unroll
                for (int i = 0; i < 16; ++i) s16[i] = sac[0][i] + sac[1][i];
                #pragma unroll
                for (int i = 0; i < 8; ++i) s8[i] = s16[i] + s16[i + 8];
                #pragma unroll
                for (int i = 0; i < 4; ++i) s4[i] = s8[i] + s8[i + 4];
                s2[0] = s4[0] + s4[2]; s2[1] = s4[1] + s4[3];
                ps = s2[0] + s2[1];
                ps += __shfl_xor(ps, 32);
            }
            if (!skip) {
                l = l * fac + ps;
                #pragma unroll
                for (int dt = 0; dt < 4; ++dt)
                    #pragma unroll
                    for (int r = 0; r < 16; ++r) oacc[dt][r] *= fac;
            } else {
                l += ps;
            }

            // ---- pack P pairs to bf16x2 ----
            unsigned pkw[2][8];
            #pragma unroll
            for (int a = 0; a < 2; ++a)
                #pragma unroll
                for (int rp = 0; rp < 8; ++rp)
                    pkw[a][rp] = (unsigned)f2bf(sac[a][2 * rp]) |
                                 ((unsigned)f2bf(sac[a][2 * rp + 1]) << 16);

            // ---- redistribute to PV B-fragments (cross-half, in-register) ----
            unsigned xp[2][8];
            #pragma unroll
            for (int a = 0; a < 2; ++a)
                #pragma unroll
                for (int i = 0; i < 8; ++i)
                    xp[a][i] = (unsigned)__shfl_xor((int)pkw[a][i], 32);

            PF8 pf[4];
            #pragma unroll
            for (int ks = 0; ks < 4; ++ks) {
                const int a = ks >> 1;
                #pragma unroll
                for (int j = 0; j < 4; ++j) {
                    const int ib = (j & 1) + 4 * (ks & 1);
                    const unsigned own_lo = pkw[a][ib];
                    const unsigned own_hi = pkw[a][ib + 2];
                    const unsigned par_lo = xp[a][ib];
                    const unsigned par_hi = xp[a][ib + 2];
                    pf[ks].u[j] = (j < 2) ? (t5 ? par_hi : own_lo)
                                          : (t5 ? own_hi : par_lo);
                }
            }

            // ---- O^T += V^T P (own kv-half of V) ----
            __builtin_amdgcn_s_setprio(1);
            #pragma unroll
            for (int dt = 0; dt < 4; ++dt) {
                #pragma unroll
                for (int ks = 0; ks < 4; ++ks) {
                    short8 vf = *(const short8*)
                        &Vt[buf][32 * dt + q5][8 * (8 * wk + ((2 * ks + t5) ^ swz))];
                    oacc[dt] = __builtin_amdgcn_mfma_f32_32x32x16_bf16(vf, pf[ks].s, oacc[dt], 0, 0, 0);
                }
            }
            __builtin_amdgcn_s_setprio(0);
        }

        asm volatile("" ::: "memory");
        __builtin_amdgcn_s_barrier();
        if (s + 2 < 17) {
            const int s2 = s + 2;
            ISSUE((s2 < nsB) ? 128 * s2 : 128 * (s2 - nsB), s & 1);
        }
    }

    EPI(QBa);
}

extern "C" void kernel_launch(void* const* d_in, const int* in_sizes, int n_in,
                              void* d_out, int out_size, void* d_ws, size_t ws_size,
                              hipStream_t stream) {
    const float* q = (const float*)d_in[0];
    const float* k = (const float*)d_in[1];
    const float* v = (const float*)d_in[2];
    float* out = (float*)d_out;
    unsigned short* Kb  = (unsigned short*)d_ws;                 // 4 MB
    unsigned short* Vtb = Kb + (size_t)8 * SEQ * 128;            // 4 MB
    prep_k<<<dim3(2048), 256, 0, stream>>>(k, Kb);
    prep_v<<<dim3(256), 256, 0, stream>>>(v, Vtb);
    attn_fwd<<<dim3(256), 512, 0, stream>>>(q, Kb, Vtb, out);
}